// Round 5
// baseline (488.913 us; speedup 1.0000x reference)
//
#include <hip/hip_runtime.h>
#include <cmath>

// Workspace layout (in floats):
//   fq_all : 0       .. 245760   (256 x (64+128+256+512))
//   r2_all : 245760  .. 253760   (4 x 2000)
//   lid    : 253760  .. 254784   (256 x 4, [b][layer])
//   G      : 262144  .. 2310144  (4 layers x 256 x 2000, FULL-K)
#define WS_FQ_OFF      0u
#define WS_R2_OFF      245760u
#define WS_LID_OFF     253760u
#define WS_G_OFF       262144u
#define G_LAYER_STRIDE 512000u
#define NREF           2000

// ---------------------------------------------------------------- pool + ref norms (one launch)
// Persistent grid-stride waves: 2304 blocks x 256 threads, each wave loops over
// many rows (long-lived blocks keep per-CU memory-level parallelism high).
// Block map:
//   [0,    512)  layer0: wave-per-row, 2048 waves x 8 rows  (HW=3136)
//   [512, 1024)  layer1: wave-per-row, 2048 waves x 16 rows (HW=784)
//   [1024,1536)  layer2: wave-per-row, 2048 waves x 32 rows (HW=196, one float4/lane)
//   [1536,2048)  layer3: wave-per-row, 2048 waves x 64 rows (HW=49, one float/lane)
//   [2048,2304)  ref norms: 1024 waves x 8 rows over 8000 (layer,row) units
__global__ __launch_bounds__(256) void pool_r2_kernel(const float* __restrict__ f0,
                                                      const float* __restrict__ f1,
                                                      const float* __restrict__ f2,
                                                      const float* __restrict__ f3,
                                                      const float* __restrict__ r0,
                                                      const float* __restrict__ r1,
                                                      const float* __restrict__ r2p,
                                                      const float* __restrict__ r3,
                                                      float* __restrict__ fq_all,
                                                      float* __restrict__ r2_all) {
    int blk = blockIdx.x;
    int t = threadIdx.x;
    int w = t >> 6, lane = t & 63;

    if (blk < 512) {
        // ---- layer0: HW=3136, 784 float4/row = 12*64 + 16 (two 6-deep batches)
        int gw = blk * 4 + w;                       // 0..2047
        for (int it = 0; it < 8; ++it) {
            size_t row = (size_t)gw + (size_t)it * 2048;
            const float4* p4 = (const float4*)(f0 + row * 3136);
            float s = 0.f;
            {
                float4 v[6];
                #pragma unroll
                for (int j = 0; j < 6; ++j) v[j] = p4[lane + j * 64];
                #pragma unroll
                for (int j = 0; j < 6; ++j) s += (v[j].x + v[j].y) + (v[j].z + v[j].w);
                #pragma unroll
                for (int j = 0; j < 6; ++j) v[j] = p4[lane + (j + 6) * 64];
                #pragma unroll
                for (int j = 0; j < 6; ++j) s += (v[j].x + v[j].y) + (v[j].z + v[j].w);
            }
            if (lane < 16) { float4 v = p4[768 + lane]; s += (v.x + v.y) + (v.z + v.w); }
            #pragma unroll
            for (int off = 32; off; off >>= 1) s += __shfl_down(s, off, 64);
            if (lane == 0) fq_all[row] = s * (1.0f / 3136.f);
        }
    } else if (blk < 1024) {
        // ---- layer1: HW=784, 196 float4/row = 3*64 + 4
        int gw = (blk - 512) * 4 + w;               // 0..2047
        for (int it = 0; it < 16; ++it) {
            size_t row = (size_t)gw + (size_t)it * 2048;
            const float4* p4 = (const float4*)(f1 + row * 784);
            float4 v0 = p4[lane];
            float4 v1 = p4[lane + 64];
            float4 v2 = p4[lane + 128];
            float s = (v0.x + v0.y) + (v0.z + v0.w)
                    + (v1.x + v1.y) + (v1.z + v1.w)
                    + (v2.x + v2.y) + (v2.z + v2.w);
            if (lane < 4) { float4 vt = p4[192 + lane]; s += (vt.x + vt.y) + (vt.z + vt.w); }
            #pragma unroll
            for (int off = 32; off; off >>= 1) s += __shfl_down(s, off, 64);
            if (lane == 0) fq_all[16384 + row] = s * (1.0f / 784.f);
        }
    } else if (blk < 1536) {
        // ---- layer2: HW=196 = 49 float4/row (row stride 784 B, 16B-aligned)
        int gw = (blk - 1024) * 4 + w;              // 0..2047
        for (int it = 0; it < 32; ++it) {
            size_t row = (size_t)gw + (size_t)it * 2048;
            const float4* p4 = (const float4*)(f2 + row * 196);
            float s = 0.f;
            if (lane < 49) { float4 v = p4[lane]; s = (v.x + v.y) + (v.z + v.w); }
            #pragma unroll
            for (int off = 32; off; off >>= 1) s += __shfl_down(s, off, 64);
            if (lane == 0) fq_all[49152 + row] = s * (1.0f / 196.f);
        }
    } else if (blk < 2048) {
        // ---- layer3: HW=49 floats/row
        int gw = (blk - 1536) * 4 + w;              // 0..2047
        for (int it = 0; it < 64; ++it) {
            size_t row = (size_t)gw + (size_t)it * 2048;
            const float* p = f3 + row * 49;
            float s = (lane < 49) ? p[lane] : 0.f;
            #pragma unroll
            for (int off = 32; off; off >>= 1) s += __shfl_down(s, off, 64);
            if (lane == 0) fq_all[114688 + row] = s * (1.0f / 49.f);
        }
    } else {
        // ---- ||ref||^2: 8000 (layer,row) units, wave-per-row
        int gw = (blk - 2048) * 4 + w;              // 0..1023
        for (int it = 0; it < 8; ++it) {
            int u = gw + it * 1024;
            if (u >= 8000) break;
            int layer = u / 2000;
            int r = u - layer * 2000;
            const float* rp; int C;
            switch (layer) {
                case 0:  rp = r0;  C = 64;  break;
                case 1:  rp = r1;  C = 128; break;
                case 2:  rp = r2p; C = 256; break;
                default: rp = r3;  C = 512; break;
            }
            const float4* rowp = (const float4*)(rp + (size_t)r * C);
            int n4 = C >> 2;
            float s = 0.f;
            for (int i = lane; i < n4; i += 64) {
                float4 v = rowp[i];
                s += v.x*v.x + v.y*v.y + v.z*v.z + v.w*v.w;
            }
            #pragma unroll
            for (int off = 32; off; off >>= 1) s += __shfl_down(s, off, 64);
            if (lane == 0) r2_all[layer * NREF + r] = s;
        }
    }
}

// ---------------------------------------------------------------- G = fq @ ref^T  (full-K, all layers)
// fp32 (no fp32 MFMA on CDNA4). 64x64 tile, BK=32, 256 threads, 4x4 acc.
// blockIdx.z = layer; each block accumulates the FULL K, writes final G once.
#define BM 64
#define BN 64
#define BK 32
#define LDT 68
__global__ __launch_bounds__(256) void gemm_all(const float* __restrict__ fq_all,
                                                const float* __restrict__ ref0,
                                                const float* __restrict__ ref1,
                                                const float* __restrict__ ref2,
                                                const float* __restrict__ ref3,
                                                float* __restrict__ G) {
    __shared__ __align__(16) float As[BK * LDT];
    __shared__ __align__(16) float Bs[BK * LDT];
    int layer = blockIdx.z;
    const float* B; int K;
    switch (layer) {
        case 0:  B = ref0; K = 64;  break;
        case 1:  B = ref1; K = 128; break;
        case 2:  B = ref2; K = 256; break;
        default: B = ref3; K = 512; break;
    }
    const int fqo[4] = {0, 16384, 49152, 114688};
    const float* A = fq_all + fqo[layer];
    float* Gout = G + (size_t)layer * G_LAYER_STRIDE;

    int t = threadIdx.x;
    int tq = t & 15, tr = t >> 4;
    int m0 = blockIdx.x * BM;
    int n0 = blockIdx.y * BN;
    int row0 = t >> 3;
    int kc4  = t & 7;
    float acc[4][4] = {};

    for (int k0 = 0; k0 < K; k0 += BK) {
        #pragma unroll
        for (int half = 0; half < 2; ++half) {
            int row = row0 + half * 32;
            float4 av = *(const float4*)(A + (size_t)(m0 + row) * K + k0 + kc4 * 4);
            int brow = n0 + row;
            float4 bv = make_float4(0.f, 0.f, 0.f, 0.f);
            if (brow < NREF) bv = *(const float4*)(B + (size_t)brow * K + k0 + kc4 * 4);
            As[(kc4*4 + 0) * LDT + row] = av.x;
            As[(kc4*4 + 1) * LDT + row] = av.y;
            As[(kc4*4 + 2) * LDT + row] = av.z;
            As[(kc4*4 + 3) * LDT + row] = av.w;
            Bs[(kc4*4 + 0) * LDT + row] = bv.x;
            Bs[(kc4*4 + 1) * LDT + row] = bv.y;
            Bs[(kc4*4 + 2) * LDT + row] = bv.z;
            Bs[(kc4*4 + 3) * LDT + row] = bv.w;
        }
        __syncthreads();
        #pragma unroll
        for (int kk = 0; kk < BK; ++kk) {
            float4 a = *(const float4*)&As[kk * LDT + tq * 4];
            float4 b = *(const float4*)&Bs[kk * LDT + tr * 4];
            acc[0][0] += a.x*b.x; acc[0][1] += a.x*b.y; acc[0][2] += a.x*b.z; acc[0][3] += a.x*b.w;
            acc[1][0] += a.y*b.x; acc[1][1] += a.y*b.y; acc[1][2] += a.y*b.z; acc[1][3] += a.y*b.w;
            acc[2][0] += a.z*b.x; acc[2][1] += a.z*b.y; acc[2][2] += a.z*b.z; acc[2][3] += a.z*b.w;
            acc[3][0] += a.w*b.x; acc[3][1] += a.w*b.y; acc[3][2] += a.w*b.z; acc[3][3] += a.w*b.w;
        }
        __syncthreads();
    }

    int rbase = n0 + tr * 4;
    if (rbase < NREF) {
        #pragma unroll
        for (int i = 0; i < 4; ++i) {
            float4 o = make_float4(acc[i][0], acc[i][1], acc[i][2], acc[i][3]);
            *(float4*)(Gout + (size_t)(m0 + tq*4 + i) * NREF + rbase) = o;
        }
    }
}

// ---------------------------------------------------------------- top-k + LID via radix histogram
// One block per (query b, layer). Positive-float bits order like uints, so
// bin = bits>>20 (11 bits, 2048 bins). LID needs only the MULTISET of the
// k+1 smallest d2: sum of logs, min (dropped NN), max (d_k) — tie-break free.
__global__ __launch_bounds__(256) void topk_lid_kernel(const float* __restrict__ fq_all,
                                                       const float* __restrict__ G_all,
                                                       const float* __restrict__ r2_all,
                                                       float* __restrict__ lid,
                                                       const int* __restrict__ kptr) {
    __shared__ __align__(16) float d2s[NREF];
    __shared__ unsigned hist[2048];          // reused as candidate buffer later
    __shared__ float redq[4], redm[4], redl[4];
    __shared__ unsigned long long red8[4];
    __shared__ int sh_B, sh_cbelow, sh_cnt;
    __shared__ float sh_dmin;

    const int Cs[4]   = {64, 128, 256, 512};
    const int fqo[4]  = {0, 16384, 49152, 114688};

    int b = blockIdx.x, layer = blockIdx.y;
    int t = threadIdx.x;
    int lane = t & 63, w = t >> 6;
    int k = kptr[0];
    if (k + 1 > NREF) k = NREF - 1;
    unsigned K1 = (unsigned)(k + 1);
    int C = Cs[layer];
    const float* fq = fq_all + fqo[layer] + (size_t)b * C;
    const float* Gb = G_all + (size_t)layer * G_LAYER_STRIDE + (size_t)b * NREF;
    const float* r2 = r2_all + layer * NREF;
    const float INF = __uint_as_float(0x7f800000u);

    // init hist + ||q||^2 partials
    for (int i = t; i < 2048; i += 256) hist[i] = 0u;
    if (t == 0) sh_cnt = 0;
    float s = 0.f;
    for (int c = t; c < C; c += 256) { float v = fq[c]; s += v * v; }
    #pragma unroll
    for (int off = 32; off; off >>= 1) s += __shfl_down(s, off, 64);
    if (lane == 0) redq[w] = s;
    __syncthreads();                                   // B1
    float q2 = redq[0] + redq[1] + redq[2] + redq[3];

    // pass A: d2 = max(q2 - 2*G + r2, 0); histogram; global min
    float minv = INF;
    for (int i = t; i < NREF / 4; i += 256) {
        float4 g = *(const float4*)(Gb + i * 4);
        float4 rr = *(const float4*)(r2 + i * 4);
        float d0 = q2 - 2.f * g.x + rr.x; d0 = d0 > 0.f ? d0 : 0.f;
        float d1 = q2 - 2.f * g.y + rr.y; d1 = d1 > 0.f ? d1 : 0.f;
        float d2_ = q2 - 2.f * g.z + rr.z; d2_ = d2_ > 0.f ? d2_ : 0.f;
        float d3 = q2 - 2.f * g.w + rr.w; d3 = d3 > 0.f ? d3 : 0.f;
        *(float4*)(d2s + i * 4) = make_float4(d0, d1, d2_, d3);
        atomicAdd(&hist[__float_as_uint(d0) >> 20], 1u);
        atomicAdd(&hist[__float_as_uint(d1) >> 20], 1u);
        atomicAdd(&hist[__float_as_uint(d2_) >> 20], 1u);
        atomicAdd(&hist[__float_as_uint(d3) >> 20], 1u);
        minv = fminf(minv, fminf(fminf(d0, d1), fminf(d2_, d3)));
    }
    #pragma unroll
    for (int off = 32; off; off >>= 1) minv = fminf(minv, __shfl_down(minv, off, 64));
    if (lane == 0) redm[w] = minv;
    __syncthreads();                                   // B2

    // wave0: scan 2048 bins (32/lane) to find bin B holding rank k+1
    if (t < 64) {
        unsigned p = 0;
        int base = t * 32;
        #pragma unroll 4
        for (int i = 0; i < 32; ++i) p += hist[base + i];
        unsigned cum = p;
        #pragma unroll
        for (int off = 1; off < 64; off <<= 1) {
            unsigned o = __shfl_up(cum, off, 64);
            if (t >= off) cum += o;
        }
        unsigned excl = cum - p;
        if (excl < K1 && K1 <= cum) {
            unsigned run = excl;
            int binB = base;
            for (int i = 0; i < 32; ++i) {
                unsigned c = hist[base + i];
                if (run + c >= K1) { binB = base + i; break; }
                run += c;
            }
            sh_B = binB;
            sh_cbelow = (int)run;
        }
        if (t == 0) sh_dmin = fminf(fminf(redm[0], redm[1]), fminf(redm[2], redm[3]));
    }
    __syncthreads();                                   // B3 (scan done; hist reusable)

    // pass B: sum logs of values strictly below bin B (< k of them); compact bin-B candidates
    int B = sh_B;
    float* cand = (float*)hist;
    float lsum = 0.f;
    for (int i = t; i < NREF; i += 256) {
        float v = d2s[i];
        int bin = (int)(__float_as_uint(v) >> 20);
        if (bin < B) {
            lsum += logf(v);
        } else if (bin == B) {
            int pos = atomicAdd(&sh_cnt, 1);
            cand[pos] = v;
        }
    }
    #pragma unroll
    for (int off = 32; off; off >>= 1) lsum += __shfl_down(lsum, off, 64);
    if (lane == 0) redl[w] = lsum;
    __syncthreads();                                   // B4

    int cnt = sh_cnt;
    int m = (int)K1 - sh_cbelow;                       // 1 <= m <= cnt
    if (cnt <= 64) {
        // selection entirely in wave0 registers — no barriers
        if (t < 64) {
            float mv = (t < cnt) ? cand[t] : INF;
            float csum = 0.f, dk = 0.f;
            for (int it = 0; it < m; ++it) {
                float x = mv;
                #pragma unroll
                for (int off = 32; off; off >>= 1) x = fminf(x, __shfl_xor(x, off, 64));
                csum += logf(x);
                dk = x;
                unsigned long long ball = __ballot(mv == x);
                int src = __ffsll(ball) - 1;
                if (t == src) mv = INF;
            }
            if (t == 0) {
                float lsum_tot = redl[0] + redl[1] + redl[2] + redl[3];
                float denom = 0.5f * (lsum_tot + csum - logf(sh_dmin) - (float)k * logf(dk));
                lid[b * 4 + layer] = -(float)k / denom;
            }
        }
    } else {
        // robust fallback: block-wide iterative argmin over candidates
        float csum = 0.f, dk = 0.f;
        for (int it = 0; it < m; ++it) {
            unsigned long long best = ~0ull;
            for (int i = t; i < cnt; i += 256) {
                unsigned long long key =
                    ((unsigned long long)__float_as_uint(cand[i]) << 32) | (unsigned)i;
                if (key < best) best = key;
            }
            #pragma unroll
            for (int off = 32; off; off >>= 1) {
                unsigned long long o = __shfl_down(best, off, 64);
                if (o < best) best = o;
            }
            if (lane == 0) red8[w] = best;
            __syncthreads();
            unsigned long long mm = red8[0];
            #pragma unroll
            for (int ww = 1; ww < 4; ++ww) if (red8[ww] < mm) mm = red8[ww];
            float v = __uint_as_float((unsigned)(mm >> 32));
            if (t == 0) {
                csum += logf(v);
                dk = v;
                cand[(int)(mm & 0xffffffffu)] = INF;
            }
            __syncthreads();
        }
        if (t == 0) {
            float lsum_tot = redl[0] + redl[1] + redl[2] + redl[3];
            float denom = 0.5f * (lsum_tot + csum - logf(sh_dmin) - (float)k * logf(dk));
            lid[b * 4 + layer] = -(float)k / denom;
        }
    }
}

// ---------------------------------------------------------------- head
__global__ __launch_bounds__(256) void head_kernel(const float* __restrict__ lid,
                                                   const float* __restrict__ w,
                                                   const float* __restrict__ bias,
                                                   float* __restrict__ out) {
    int b = threadIdx.x;
    float acc = bias[0];
    #pragma unroll
    for (int l = 0; l < 4; ++l) acc += lid[b * 4 + l] * w[l];
    out[b] = 1.f / (1.f + expf(-acc));
}

extern "C" void kernel_launch(void* const* d_in, const int* in_sizes, int n_in,
                              void* d_out, int out_size, void* d_ws, size_t ws_size,
                              hipStream_t stream) {
    // dict order: feat0, ref0, feat1, ref1, feat2, ref2, feat3, ref3, reg_w, reg_b, k
    const float* feat[4] = {(const float*)d_in[0], (const float*)d_in[2],
                            (const float*)d_in[4], (const float*)d_in[6]};
    const float* ref[4]  = {(const float*)d_in[1], (const float*)d_in[3],
                            (const float*)d_in[5], (const float*)d_in[7]};
    const float* reg_w = (const float*)d_in[8];
    const float* reg_b = (const float*)d_in[9];
    const int*   kptr  = (const int*)d_in[10];

    float* ws     = (float*)d_ws;
    float* fq_all = ws + WS_FQ_OFF;
    float* r2_all = ws + WS_R2_OFF;
    float* lid    = ws + WS_LID_OFF;
    float* G      = ws + WS_G_OFF;

    // 1) pool all 4 layers + ref-norms, persistent grid-stride waves (2304 blocks)
    pool_r2_kernel<<<2304, 256, 0, stream>>>(
        feat[0], feat[1], feat[2], feat[3],
        ref[0], ref[1], ref[2], ref[3],
        fq_all, r2_all);

    // 2) all 4 layer GEMMs in one launch, full-K
    gemm_all<<<dim3(256 / BM, (NREF + BN - 1) / BN, 4), 256, 0, stream>>>(
        fq_all, ref[0], ref[1], ref[2], ref[3], G);

    // 3) top-k + LID
    topk_lid_kernel<<<dim3(256, 4), 256, 0, stream>>>(fq_all, G, r2_all, lid, kptr);

    // 4) head
    head_kernel<<<1, 256, 0, stream>>>(lid, reg_w, reg_b, (float*)d_out);
}

// Round 6
// 454.674 us; speedup vs baseline: 1.0753x; 1.0753x over previous
//
#include <hip/hip_runtime.h>
#include <cmath>

// Workspace layout (in floats):
//   fq_all : 0       .. 245760   (256 x (64+128+256+512))
//   r2_all : 245760  .. 253760   (4 x 2000)
//   lid    : 253760  .. 254784   (256 x 4, [b][layer])
//   G      : 262144  .. 2310144  (4 layers x 256 x 2000, FULL-K)
#define WS_FQ_OFF      0u
#define WS_R2_OFF      245760u
#define WS_LID_OFF     253760u
#define WS_G_OFF       262144u
#define G_LAYER_STRIDE 512000u
#define NREF           2000

// ---------------------------------------------------------------- pool + ref norms (one launch)
// LDS-staged streaming pool. Every tile = 12,544 contiguous floats (50,176 B):
//   L0: 4 rows x 3136   L1: 16 rows x 784   L2: 64 rows x 196   L3: 256 rows x 49
// Stage: 256 threads x (12 float4 + tail) coalesced, dependency-free (max MLP).
// Reduce: every thread sums exactly 49 scalars from LDS (bank-conflict-free
// mappings: stride-49 starts, gcd(49,32)=1; L0 lane-strided), then shuffle
// combine within row group. One barrier per tile.
// Block map: [0,4096) L0 | [4096,6144) L1 | [6144,7168) L2 | [7168,7680) L3 |
//            [7680,8180) ref norms (wave-per-row, 4 rows/block).
__global__ __launch_bounds__(256) void pool_r2_kernel(const float* __restrict__ f0,
                                                      const float* __restrict__ f1,
                                                      const float* __restrict__ f2,
                                                      const float* __restrict__ f3,
                                                      const float* __restrict__ r0,
                                                      const float* __restrict__ r1,
                                                      const float* __restrict__ r2p,
                                                      const float* __restrict__ r3,
                                                      float* __restrict__ fq_all,
                                                      float* __restrict__ r2_all) {
    __shared__ __align__(16) float tile[12544];
    int blk = blockIdx.x;
    int t = threadIdx.x;
    int w = t >> 6, lane = t & 63;

    if (blk < 7680) {
        // ------- select layer / tile geometry
        const float* src; float inv; int fqbase; int rows0;
        if (blk < 4096)      { src = f0 + (size_t)blk * 12544;          inv = 1.0f/3136.f; fqbase = 0;      rows0 = blk * 4;            }
        else if (blk < 6144) { src = f1 + (size_t)(blk - 4096) * 12544; inv = 1.0f/784.f;  fqbase = 16384;  rows0 = (blk - 4096) * 16;  }
        else if (blk < 7168) { src = f2 + (size_t)(blk - 6144) * 12544; inv = 1.0f/196.f;  fqbase = 49152;  rows0 = (blk - 6144) * 64;  }
        else                 { src = f3 + (size_t)(blk - 7168) * 12544; inv = 1.0f/49.f;   fqbase = 114688; rows0 = (blk - 7168) * 256; }

        // ------- stage 3136 float4 (coalesced, independent loads)
        {
            const float4* g4 = (const float4*)src;
            float4* l4 = (float4*)tile;
            float4 v[12];
            #pragma unroll
            for (int j = 0; j < 12; ++j) v[j] = g4[t + j * 256];
            float4 vt;
            if (t < 64) vt = g4[3072 + t];
            #pragma unroll
            for (int j = 0; j < 12; ++j) l4[t + j * 256] = v[j];
            if (t < 64) l4[3072 + t] = vt;
        }
        __syncthreads();

        // ------- reduce: every thread sums exactly 49 scalars
        if (blk < 4096) {
            // L0: wave-per-row, lane-strided (conflict-free: consecutive banks)
            const float* rp = tile + w * 3136;
            float s = 0.f;
            #pragma unroll
            for (int j = 0; j < 49; ++j) s += rp[j * 64 + lane];
            #pragma unroll
            for (int off = 32; off; off >>= 1) s += __shfl_down(s, off, 64);
            if (lane == 0) fq_all[rows0 + w] = s * inv;
        } else if (blk < 6144) {
            // L1: 16 threads/row, start = row*784 + p*49 (banks distinct mod 32)
            int row = t >> 4, p = t & 15;
            const float* rp = tile + row * 784 + p * 49;
            float s = 0.f;
            #pragma unroll
            for (int j = 0; j < 49; ++j) s += rp[j];
            s += __shfl_xor(s, 8, 64);
            s += __shfl_xor(s, 4, 64);
            s += __shfl_xor(s, 2, 64);
            s += __shfl_xor(s, 1, 64);
            if (p == 0) fq_all[fqbase + rows0 + row] = s * inv;
        } else if (blk < 7168) {
            // L2: 4 threads/row, start = row*196 + p*49 (banks distinct mod 32)
            int row = t >> 2, p = t & 3;
            const float* rp = tile + row * 196 + p * 49;
            float s = 0.f;
            #pragma unroll
            for (int j = 0; j < 49; ++j) s += rp[j];
            s += __shfl_xor(s, 2, 64);
            s += __shfl_xor(s, 1, 64);
            if (p == 0) fq_all[fqbase + rows0 + row] = s * inv;
        } else {
            // L3: thread-per-row, start = t*49 (2-way alias only: free)
            const float* rp = tile + t * 49;
            float s = 0.f;
            #pragma unroll
            for (int j = 0; j < 49; ++j) s += rp[j];
            fq_all[fqbase + rows0 + t] = s * inv;
        }
    } else {
        // ------- ||ref||^2, wave-per-row, 4 rows/block (500 blocks x 4 = 2000)
        int r4 = (blk - 7680) * 4 + w;
        int layer = r4 >> 9;                     // 2000 rows -> 500 per... no:
        // r4 in [0,2000): map 500 blocks x 4 waves to (layer,row) as before:
        // use flat unit u = r4 over 2000 rows of each layer sequentially is wrong;
        // instead: 2000 wave-slots cover layer l = u/500? No — keep simple:
        // 500 blocks x 4 waves = 2000 wave-rows; iterate 4 layers inside.
        (void)layer;
        int r = r4;                               // 0..1999
        if (r < NREF) {
            #pragma unroll 1
            for (int l = 0; l < 4; ++l) {
                const float* rp; int C;
                switch (l) {
                    case 0:  rp = r0;  C = 64;  break;
                    case 1:  rp = r1;  C = 128; break;
                    case 2:  rp = r2p; C = 256; break;
                    default: rp = r3;  C = 512; break;
                }
                const float4* rowp = (const float4*)(rp + (size_t)r * C);
                int n4 = C >> 2;
                float s = 0.f;
                for (int i = lane; i < n4; i += 64) {
                    float4 v = rowp[i];
                    s += v.x*v.x + v.y*v.y + v.z*v.z + v.w*v.w;
                }
                #pragma unroll
                for (int off = 32; off; off >>= 1) s += __shfl_down(s, off, 64);
                if (lane == 0) r2_all[l * NREF + r] = s;
            }
        }
    }
}

// ---------------------------------------------------------------- G = fq @ ref^T  (full-K, all layers)
// fp32 (no fp32 MFMA on CDNA4). 64x64 tile, BK=32, 256 threads, 4x4 acc.
// blockIdx.z = layer; each block accumulates the FULL K, writes final G once.
#define BM 64
#define BN 64
#define BK 32
#define LDT 68
__global__ __launch_bounds__(256) void gemm_all(const float* __restrict__ fq_all,
                                                const float* __restrict__ ref0,
                                                const float* __restrict__ ref1,
                                                const float* __restrict__ ref2,
                                                const float* __restrict__ ref3,
                                                float* __restrict__ G) {
    __shared__ __align__(16) float As[BK * LDT];
    __shared__ __align__(16) float Bs[BK * LDT];
    int layer = blockIdx.z;
    const float* B; int K;
    switch (layer) {
        case 0:  B = ref0; K = 64;  break;
        case 1:  B = ref1; K = 128; break;
        case 2:  B = ref2; K = 256; break;
        default: B = ref3; K = 512; break;
    }
    const int fqo[4] = {0, 16384, 49152, 114688};
    const float* A = fq_all + fqo[layer];
    float* Gout = G + (size_t)layer * G_LAYER_STRIDE;

    int t = threadIdx.x;
    int tq = t & 15, tr = t >> 4;
    int m0 = blockIdx.x * BM;
    int n0 = blockIdx.y * BN;
    int row0 = t >> 3;
    int kc4  = t & 7;
    float acc[4][4] = {};

    for (int k0 = 0; k0 < K; k0 += BK) {
        #pragma unroll
        for (int half = 0; half < 2; ++half) {
            int row = row0 + half * 32;
            float4 av = *(const float4*)(A + (size_t)(m0 + row) * K + k0 + kc4 * 4);
            int brow = n0 + row;
            float4 bv = make_float4(0.f, 0.f, 0.f, 0.f);
            if (brow < NREF) bv = *(const float4*)(B + (size_t)brow * K + k0 + kc4 * 4);
            As[(kc4*4 + 0) * LDT + row] = av.x;
            As[(kc4*4 + 1) * LDT + row] = av.y;
            As[(kc4*4 + 2) * LDT + row] = av.z;
            As[(kc4*4 + 3) * LDT + row] = av.w;
            Bs[(kc4*4 + 0) * LDT + row] = bv.x;
            Bs[(kc4*4 + 1) * LDT + row] = bv.y;
            Bs[(kc4*4 + 2) * LDT + row] = bv.z;
            Bs[(kc4*4 + 3) * LDT + row] = bv.w;
        }
        __syncthreads();
        #pragma unroll
        for (int kk = 0; kk < BK; ++kk) {
            float4 a = *(const float4*)&As[kk * LDT + tq * 4];
            float4 b = *(const float4*)&Bs[kk * LDT + tr * 4];
            acc[0][0] += a.x*b.x; acc[0][1] += a.x*b.y; acc[0][2] += a.x*b.z; acc[0][3] += a.x*b.w;
            acc[1][0] += a.y*b.x; acc[1][1] += a.y*b.y; acc[1][2] += a.y*b.z; acc[1][3] += a.y*b.w;
            acc[2][0] += a.z*b.x; acc[2][1] += a.z*b.y; acc[2][2] += a.z*b.z; acc[2][3] += a.z*b.w;
            acc[3][0] += a.w*b.x; acc[3][1] += a.w*b.y; acc[3][2] += a.w*b.z; acc[3][3] += a.w*b.w;
        }
        __syncthreads();
    }

    int rbase = n0 + tr * 4;
    if (rbase < NREF) {
        #pragma unroll
        for (int i = 0; i < 4; ++i) {
            float4 o = make_float4(acc[i][0], acc[i][1], acc[i][2], acc[i][3]);
            *(float4*)(Gout + (size_t)(m0 + tq*4 + i) * NREF + rbase) = o;
        }
    }
}

// ---------------------------------------------------------------- top-k + LID via radix histogram
// One block per (query b, layer). Positive-float bits order like uints, so
// bin = bits>>20 (11 bits, 2048 bins). LID needs only the MULTISET of the
// k+1 smallest d2: sum of logs, min (dropped NN), max (d_k) — tie-break free.
__global__ __launch_bounds__(256) void topk_lid_kernel(const float* __restrict__ fq_all,
                                                       const float* __restrict__ G_all,
                                                       const float* __restrict__ r2_all,
                                                       float* __restrict__ lid,
                                                       const int* __restrict__ kptr) {
    __shared__ __align__(16) float d2s[NREF];
    __shared__ unsigned hist[2048];          // reused as candidate buffer later
    __shared__ float redq[4], redm[4], redl[4];
    __shared__ unsigned long long red8[4];
    __shared__ int sh_B, sh_cbelow, sh_cnt;
    __shared__ float sh_dmin;

    const int Cs[4]   = {64, 128, 256, 512};
    const int fqo[4]  = {0, 16384, 49152, 114688};

    int b = blockIdx.x, layer = blockIdx.y;
    int t = threadIdx.x;
    int lane = t & 63, w = t >> 6;
    int k = kptr[0];
    if (k + 1 > NREF) k = NREF - 1;
    unsigned K1 = (unsigned)(k + 1);
    int C = Cs[layer];
    const float* fq = fq_all + fqo[layer] + (size_t)b * C;
    const float* Gb = G_all + (size_t)layer * G_LAYER_STRIDE + (size_t)b * NREF;
    const float* r2 = r2_all + layer * NREF;
    const float INF = __uint_as_float(0x7f800000u);

    // init hist + ||q||^2 partials
    for (int i = t; i < 2048; i += 256) hist[i] = 0u;
    if (t == 0) sh_cnt = 0;
    float s = 0.f;
    for (int c = t; c < C; c += 256) { float v = fq[c]; s += v * v; }
    #pragma unroll
    for (int off = 32; off; off >>= 1) s += __shfl_down(s, off, 64);
    if (lane == 0) redq[w] = s;
    __syncthreads();                                   // B1
    float q2 = redq[0] + redq[1] + redq[2] + redq[3];

    // pass A: d2 = max(q2 - 2*G + r2, 0); histogram; global min
    float minv = INF;
    for (int i = t; i < NREF / 4; i += 256) {
        float4 g = *(const float4*)(Gb + i * 4);
        float4 rr = *(const float4*)(r2 + i * 4);
        float d0 = q2 - 2.f * g.x + rr.x; d0 = d0 > 0.f ? d0 : 0.f;
        float d1 = q2 - 2.f * g.y + rr.y; d1 = d1 > 0.f ? d1 : 0.f;
        float d2_ = q2 - 2.f * g.z + rr.z; d2_ = d2_ > 0.f ? d2_ : 0.f;
        float d3 = q2 - 2.f * g.w + rr.w; d3 = d3 > 0.f ? d3 : 0.f;
        *(float4*)(d2s + i * 4) = make_float4(d0, d1, d2_, d3);
        atomicAdd(&hist[__float_as_uint(d0) >> 20], 1u);
        atomicAdd(&hist[__float_as_uint(d1) >> 20], 1u);
        atomicAdd(&hist[__float_as_uint(d2_) >> 20], 1u);
        atomicAdd(&hist[__float_as_uint(d3) >> 20], 1u);
        minv = fminf(minv, fminf(fminf(d0, d1), fminf(d2_, d3)));
    }
    #pragma unroll
    for (int off = 32; off; off >>= 1) minv = fminf(minv, __shfl_down(minv, off, 64));
    if (lane == 0) redm[w] = minv;
    __syncthreads();                                   // B2

    // wave0: scan 2048 bins (32/lane) to find bin B holding rank k+1
    if (t < 64) {
        unsigned p = 0;
        int base = t * 32;
        #pragma unroll 4
        for (int i = 0; i < 32; ++i) p += hist[base + i];
        unsigned cum = p;
        #pragma unroll
        for (int off = 1; off < 64; off <<= 1) {
            unsigned o = __shfl_up(cum, off, 64);
            if (t >= off) cum += o;
        }
        unsigned excl = cum - p;
        if (excl < K1 && K1 <= cum) {
            unsigned run = excl;
            int binB = base;
            for (int i = 0; i < 32; ++i) {
                unsigned c = hist[base + i];
                if (run + c >= K1) { binB = base + i; break; }
                run += c;
            }
            sh_B = binB;
            sh_cbelow = (int)run;
        }
        if (t == 0) sh_dmin = fminf(fminf(redm[0], redm[1]), fminf(redm[2], redm[3]));
    }
    __syncthreads();                                   // B3 (scan done; hist reusable)

    // pass B: sum logs of values strictly below bin B (< k of them); compact bin-B candidates
    int B = sh_B;
    float* cand = (float*)hist;
    float lsum = 0.f;
    for (int i = t; i < NREF; i += 256) {
        float v = d2s[i];
        int bin = (int)(__float_as_uint(v) >> 20);
        if (bin < B) {
            lsum += logf(v);
        } else if (bin == B) {
            int pos = atomicAdd(&sh_cnt, 1);
            cand[pos] = v;
        }
    }
    #pragma unroll
    for (int off = 32; off; off >>= 1) lsum += __shfl_down(lsum, off, 64);
    if (lane == 0) redl[w] = lsum;
    __syncthreads();                                   // B4

    int cnt = sh_cnt;
    int m = (int)K1 - sh_cbelow;                       // 1 <= m <= cnt
    if (cnt <= 64) {
        // selection entirely in wave0 registers — no barriers
        if (t < 64) {
            float mv = (t < cnt) ? cand[t] : INF;
            float csum = 0.f, dk = 0.f;
            for (int it = 0; it < m; ++it) {
                float x = mv;
                #pragma unroll
                for (int off = 32; off; off >>= 1) x = fminf(x, __shfl_xor(x, off, 64));
                csum += logf(x);
                dk = x;
                unsigned long long ball = __ballot(mv == x);
                int src = __ffsll(ball) - 1;
                if (t == src) mv = INF;
            }
            if (t == 0) {
                float lsum_tot = redl[0] + redl[1] + redl[2] + redl[3];
                float denom = 0.5f * (lsum_tot + csum - logf(sh_dmin) - (float)k * logf(dk));
                lid[b * 4 + layer] = -(float)k / denom;
            }
        }
    } else {
        // robust fallback: block-wide iterative argmin over candidates
        float csum = 0.f, dk = 0.f;
        for (int it = 0; it < m; ++it) {
            unsigned long long best = ~0ull;
            for (int i = t; i < cnt; i += 256) {
                unsigned long long key =
                    ((unsigned long long)__float_as_uint(cand[i]) << 32) | (unsigned)i;
                if (key < best) best = key;
            }
            #pragma unroll
            for (int off = 32; off; off >>= 1) {
                unsigned long long o = __shfl_down(best, off, 64);
                if (o < best) best = o;
            }
            if (lane == 0) red8[w] = best;
            __syncthreads();
            unsigned long long mm = red8[0];
            #pragma unroll
            for (int ww = 1; ww < 4; ++ww) if (red8[ww] < mm) mm = red8[ww];
            float v = __uint_as_float((unsigned)(mm >> 32));
            if (t == 0) {
                csum += logf(v);
                dk = v;
                cand[(int)(mm & 0xffffffffu)] = INF;
            }
            __syncthreads();
        }
        if (t == 0) {
            float lsum_tot = redl[0] + redl[1] + redl[2] + redl[3];
            float denom = 0.5f * (lsum_tot + csum - logf(sh_dmin) - (float)k * logf(dk));
            lid[b * 4 + layer] = -(float)k / denom;
        }
    }
}

// ---------------------------------------------------------------- head
__global__ __launch_bounds__(256) void head_kernel(const float* __restrict__ lid,
                                                   const float* __restrict__ w,
                                                   const float* __restrict__ bias,
                                                   float* __restrict__ out) {
    int b = threadIdx.x;
    float acc = bias[0];
    #pragma unroll
    for (int l = 0; l < 4; ++l) acc += lid[b * 4 + l] * w[l];
    out[b] = 1.f / (1.f + expf(-acc));
}

extern "C" void kernel_launch(void* const* d_in, const int* in_sizes, int n_in,
                              void* d_out, int out_size, void* d_ws, size_t ws_size,
                              hipStream_t stream) {
    // dict order: feat0, ref0, feat1, ref1, feat2, ref2, feat3, ref3, reg_w, reg_b, k
    const float* feat[4] = {(const float*)d_in[0], (const float*)d_in[2],
                            (const float*)d_in[4], (const float*)d_in[6]};
    const float* ref[4]  = {(const float*)d_in[1], (const float*)d_in[3],
                            (const float*)d_in[5], (const float*)d_in[7]};
    const float* reg_w = (const float*)d_in[8];
    const float* reg_b = (const float*)d_in[9];
    const int*   kptr  = (const int*)d_in[10];

    float* ws     = (float*)d_ws;
    float* fq_all = ws + WS_FQ_OFF;
    float* r2_all = ws + WS_R2_OFF;
    float* lid    = ws + WS_LID_OFF;
    float* G      = ws + WS_G_OFF;

    // 1) pool (LDS-staged streaming tiles) + ref-norms, 8180 blocks
    pool_r2_kernel<<<8180, 256, 0, stream>>>(
        feat[0], feat[1], feat[2], feat[3],
        ref[0], ref[1], ref[2], ref[3],
        fq_all, r2_all);

    // 2) all 4 layer GEMMs in one launch, full-K
    gemm_all<<<dim3(256 / BM, (NREF + BN - 1) / BN, 4), 256, 0, stream>>>(
        fq_all, ref[0], ref[1], ref[2], ref[3], G);

    // 3) top-k + LID
    topk_lid_kernel<<<dim3(256, 4), 256, 0, stream>>>(fq_all, G, r2_all, lid, kptr);

    // 4) head
    head_kernel<<<1, 256, 0, stream>>>(lid, reg_w, reg_b, (float*)d_out);
}